// Round 14
// baseline (157.941 us; speedup 1.0000x reference)
//
#include <hip/hip_runtime.h>

typedef unsigned short u16;
typedef unsigned int u32;
typedef __attribute__((ext_vector_type(4))) unsigned short u16x4;
typedef __attribute__((ext_vector_type(8))) short short8;
typedef __attribute__((ext_vector_type(8))) __bf16 bf16x8;
typedef __attribute__((ext_vector_type(4))) float f32x4;

#define T_STEPS 16384
#define INP 1024
#define SDIM 512
#define NGEMM 2048   // 4 gates * 512
#define L2E 1.4426950408889634f

__device__ __forceinline__ u16 f2bf(float f) {
    unsigned u = __float_as_uint(f);
    return (u16)((u + 0x7fffu + ((u >> 16) & 1u)) >> 16);
}
__device__ __forceinline__ float bfhi(u32 d) { return __uint_as_float(d & 0xffff0000u); }
__device__ __forceinline__ float bflo(u32 d) { return __uint_as_float(d << 16); }

__device__ __forceinline__ void gload_lds16(const void* g, void* l) {
    __builtin_amdgcn_global_load_lds((const __attribute__((address_space(1))) unsigned*)g,
                                     (__attribute__((address_space(3))) unsigned*)l, 16, 0, 0);
}

// ---------- convert x (T,1024) fp32 -> bf16 ----------
__global__ void cvt_x(const float* __restrict__ x, u16* __restrict__ xb, long n4) {
    long i = (long)blockIdx.x * blockDim.x + threadIdx.x;
    long stride = (long)gridDim.x * blockDim.x;
    for (; i < n4; i += stride) {
        float4 v = ((const float4*)x)[i];
        u16x4 o;
        o.x = f2bf(v.x); o.y = f2bf(v.y); o.z = f2bf(v.z); o.w = f2bf(v.w);
        ((u16x4*)xb)[i] = o;
    }
}

// ---------- pack weight_input (512,4,1024) fp32 -> bf16 (2048,1024) with n = g*512+s ----------
__global__ void pack_w(const float* __restrict__ w, u16* __restrict__ wb) {
    int id = blockIdx.x * blockDim.x + threadIdx.x;
    int kv = id & 255;          // k/4
    int n  = id >> 8;           // 0..2047
    int g = n >> 9, s = n & 511;
    const float4 v = *(const float4*)(w + ((long)(s * 4 + g)) * INP + kv * 4);
    u16x4 o;
    o.x = f2bf(v.x); o.y = f2bf(v.y); o.z = f2bf(v.z); o.w = f2bf(v.w);
    *(u16x4*)(wb + (long)n * INP + kv * 4) = o;
}

// ---------- GEMM: 256x256, 8 waves, 4-buf ring, 1 BARRIER/ITER, depth-2 stage ----------
// Iter t (read buf t%4, stage tile t+2 -> buf (t+2)%4):
//   vmcnt(4) ; barrier ; ds_read afr0-3+bfr (8) ; STAGE ; lgkm(0) ; prio1 ;
//   16 MFMA ; prio0 ; ds_read afr4-7 (4) ; lgkm(0) ; prio1 ; 16 MFMA ; prio0
// FIFO audit (4 loads/iter): entry-of-t outstanding = {tile t, t+1} <= 8 ->
// vmcnt(4) waits exactly tile t, ISSUED 2 ITERS (~4000cy) EARLIER -> never
// blocks steady-state. Barrier then makes all waves' tile-t writes visible.
// Overwrite safety: STAGE at t writes buf (t-2)%4; its readers (iter t-2)
// retired own reads via lgkm(0) before the t-1 barrier; t's barrier precedes
// the STAGE. Tail: t=28/29 stage tiles 30/31 (bufs 2/3); t=30 vmcnt(4)
// (outstanding 30,31); t=31 vmcnt(0). Prologue: stage tiles 0,1 only.
// Swizzle (R7, conflicts=0): lds[row][slot]=chunk slot^((row>>1)&3); stage
// thread fetches chunk (lane&3)^((row0>>1)&3); reader reads kq^((r16>>1)&3).
// XCD swizzle: 512 blocks %8==0. Epilogue: permuted coef layout, uint4 stores
// (R12, WRITE_SIZE verified exactly 131072 KB).
__global__ __launch_bounds__(512, 2) void gemm_bt(const u16* __restrict__ A,
                                                  const u16* __restrict__ B,
                                                  const float* __restrict__ wrec,
                                                  const float* __restrict__ bsv,
                                                  u32* __restrict__ coef,
                                                  int M, int N, int K) {
    __shared__ u16 sA[4][256 * 32];
    __shared__ u16 sB[4][256 * 32];
    const int tid = threadIdx.x;
    const int nbx = N >> 8;                 // 8
    const int nwg = gridDim.x;              // 512
    const int cpx = nwg >> 3;
    const int bid = ((int)blockIdx.x & 7) * cpx + ((int)blockIdx.x >> 3);
    const int bx = bid % nbx, by = bid / nbx;
    const long brow = (long)by << 8, bcol = (long)bx << 8;
    const int w = tid >> 6, lane = tid & 63;
    const int wr = w >> 2, wc = w & 3;      // 2 x 4 waves
    const int r16 = lane & 15, kq = lane >> 4;

    // staging: each wave stages rows [w*32, w*32+32) of A and B (2 gloads each)
    const int row0  = w * 32 + (lane >> 2);
    const int sslot = lane & 3;
    const int chs   = sslot ^ ((row0 >> 1) & 3);
    const u16* gA0 = A + (brow + row0) * (long)K + chs * 8;
    const u16* gA1 = gA0 + 16 * (long)K;
    const u16* gB0 = B + (bcol + row0) * (long)K + chs * 8;
    const u16* gB1 = gB0 + 16 * (long)K;
    const int dst0 = row0 * 32 + sslot * 8;
    const int dst1 = dst0 + 16 * 32;

    const int slotR = kq ^ ((r16 >> 1) & 3);
    int aoff[8], boff[4];
    #pragma unroll
    for (int m = 0; m < 8; ++m)
        aoff[m] = (wr * 128 + m * 16 + r16) * 32 + slotR * 8;
    #pragma unroll
    for (int n = 0; n < 4; ++n)
        boff[n] = (wc * 64 + n * 16 + r16) * 32 + slotR * 8;

    f32x4 acc[8][4] = {};

#define STAGE(BUF, koff) do { \
        gload_lds16(gA0 + (koff), &sA[BUF][dst0]); \
        gload_lds16(gA1 + (koff), &sA[BUF][dst1]); \
        gload_lds16(gB0 + (koff), &sB[BUF][dst0]); \
        gload_lds16(gB1 + (koff), &sB[BUF][dst1]); \
    } while (0)

#define ITER(BUF, SBUF, SKOFF, WAITSTR, DOSTAGE) do { \
        asm volatile(WAITSTR ::: "memory"); \
        __builtin_amdgcn_s_barrier(); \
        bf16x8 afr[4], bfr[4]; \
        _Pragma("unroll") for (int m_ = 0; m_ < 4; ++m_) \
            afr[m_] = *(const bf16x8*)&sA[BUF][aoff[m_]]; \
        _Pragma("unroll") for (int n_ = 0; n_ < 4; ++n_) \
            bfr[n_] = *(const bf16x8*)&sB[BUF][boff[n_]]; \
        if (DOSTAGE) { STAGE(SBUF, SKOFF); } \
        asm volatile("s_waitcnt lgkmcnt(0)" ::: "memory"); \
        __builtin_amdgcn_s_setprio(1); \
        _Pragma("unroll") for (int m_ = 0; m_ < 4; ++m_) \
            _Pragma("unroll") for (int n_ = 0; n_ < 4; ++n_) \
                acc[m_][n_] = __builtin_amdgcn_mfma_f32_16x16x32_bf16(afr[m_], bfr[n_], acc[m_][n_], 0, 0, 0); \
        __builtin_amdgcn_s_setprio(0); \
        bf16x8 af2[4]; \
        _Pragma("unroll") for (int m_ = 0; m_ < 4; ++m_) \
            af2[m_] = *(const bf16x8*)&sA[BUF][aoff[4 + m_]]; \
        asm volatile("s_waitcnt lgkmcnt(0)" ::: "memory"); \
        __builtin_amdgcn_s_setprio(1); \
        _Pragma("unroll") for (int m_ = 0; m_ < 4; ++m_) \
            _Pragma("unroll") for (int n_ = 0; n_ < 4; ++n_) \
                acc[4 + m_][n_] = __builtin_amdgcn_mfma_f32_16x16x32_bf16(af2[m_], bfr[n_], acc[4 + m_][n_], 0, 0, 0); \
        __builtin_amdgcn_s_setprio(0); \
    } while (0)

    // prologue: tiles 0,1 -> bufs 0,1 (8 loads outstanding)
    STAGE(0, 0);
    STAGE(1, 32);

    // main: t=0..27 (x4 unroll); iter t stages tile t+2 into buf (t+2)%4
    #pragma unroll 1
    for (int t = 0; t < 28; t += 4) {
        ITER(0, 2, (t + 2) * 32, "s_waitcnt vmcnt(4)", 1);
        ITER(1, 3, (t + 3) * 32, "s_waitcnt vmcnt(4)", 1);
        ITER(2, 0, (t + 4) * 32, "s_waitcnt vmcnt(4)", 1);
        ITER(3, 1, (t + 5) * 32, "s_waitcnt vmcnt(4)", 1);
    }
    ITER(0, 2, 30 * 32, "s_waitcnt vmcnt(4)", 1);   // t=28: stage tile 30
    ITER(1, 3, 31 * 32, "s_waitcnt vmcnt(4)", 1);   // t=29: stage tile 31
    ITER(2, 0, 0,       "s_waitcnt vmcnt(4)", 0);   // t=30: wait tile 30
    ITER(3, 0, 0,       "s_waitcnt vmcnt(0)", 0);   // t=31: wait tile 31
#undef ITER
#undef STAGE

    // ---- epilogue: linearized coeffs, PERMUTED layout, coalesced uint4 stores ----
    const int g = (int)(bcol >> 9);                  // block-uniform gate
    float wvv[4], bvv[4];
    #pragma unroll
    for (int n = 0; n < 4; ++n) {
        long col = bcol + wc * 64 + n * 16 + r16;
        wvv[n] = wrec[col]; bvv[n] = bsv[col];
    }
    #pragma unroll
    for (int m = 0; m < 8; ++m) {
        #pragma unroll
        for (int j = 0; j < 4; ++j) {
            u32 pk[4];
            #pragma unroll
            for (int n = 0; n < 4; ++n) {
                float z0 = acc[m][n][j] + bvv[n];
                if (g == 3) {
                    float et = __builtin_amdgcn_exp2f(-2.f * L2E * z0);
                    float r = __builtin_amdgcn_rcpf(1.f + et);
                    float t = __builtin_fmaf(2.f, r, -1.f);
                    pk[n] = ((u32)f2bf(t) << 16) | f2bf((1.f - t * t) * wvv[n]);
                } else {
                    float e = __builtin_amdgcn_exp2f(-L2E * z0);
                    float r = __builtin_amdgcn_rcpf(1.f + e);
                    float kk = (g == 0) ? 1.f : ((g == 1) ? (-2.f * L2E) : 2.f);
                    float C0 = kk * r;
                    pk[n] = ((u32)f2bf(C0) << 16) | f2bf(C0 * r * e * wvv[n]);
                }
            }
            long row = brow + wr * 128 + m * 16 + kq * 4 + j;
            uint4 v4; v4.x = pk[0]; v4.y = pk[1]; v4.z = pk[2]; v4.w = pk[3];
            *(uint4*)(coef + row * NGEMM + bcol + wc * 64 + r16 * 4) = v4;
        }
    }
}

// ---------- diagonal LSTM scan, parallel-in-time ----------
// 32 time-chunks x 8 channel-groups = 256 blocks; 64-step warm-up (see R5).
// Consumer lane L owns channel s_own = blk64 + (L&3)*16 + (L>>2) to match the
// gemm epilogue's permuted coef layout (LDS position L holds that channel).
#define CHUNK 64
#define LCHUNK 512
#define NPAR (T_STEPS / LCHUNK)   // 32
#define PF 4

#define STEP(U) do { \
    float fh  = __builtin_fmaf(bflo((U)[0]), h, bfhi((U)[0])); \
    float ia  = __builtin_fmaf(bflo((U)[1]), h, bfhi((U)[1])); \
    float oo2 = __builtin_fmaf(bflo((U)[2]), h, bfhi((U)[2])); \
    float gb  = __builtin_fmaf(bflo((U)[3]), h, bfhi((U)[3])); \
    float ign = ia * gb; \
    float negoo = -0.5f * oo2; \
    c2 = __builtin_fmaf(fh, c2, ign); \
    float rt = __builtin_amdgcn_rcpf(1.f + __builtin_amdgcn_exp2f(c2)); \
    h = __builtin_fmaf(oo2, rt, negoo); \
    cval = c2 * CK; \
} while (0)

__global__ __launch_bounds__(128) void lstm_scan(const u32* __restrict__ coef,
                                                 float* __restrict__ h_out,
                                                 float* __restrict__ c_out) {
    __shared__ u32 lds[2][CHUNK][256];   // 128 KiB
    const int tid = threadIdx.x;
    const int lane = tid & 63;
    const int blk_ch = blockIdx.x & 7;
    const int chunk = blockIdx.x >> 3;
    const int warm = (chunk == 0) ? 0 : 1;
    const long tstart = (long)chunk * LCHUNK - (long)warm * CHUNK;
    const int NC = LCHUNK / CHUNK + warm;

    if (tid >= 64) {
        const u32* src = coef + tstart * NGEMM + (lane >> 4) * SDIM + blk_ch * 64 + (lane & 15) * 4;
        #pragma unroll 8
        for (int j = 0; j < CHUNK; ++j)
            gload_lds16(src + (long)j * NGEMM, &lds[0][j][0]);
        __syncthreads();
        for (int k = 0; k < NC; ++k) {
            if (k + 1 < NC) {
                const u32* s2 = src + (long)(k + 1) * CHUNK * NGEMM;
                u32* dst = &lds[(k + 1) & 1][0][0];
                #pragma unroll 8
                for (int j = 0; j < CHUNK; ++j)
                    gload_lds16(s2 + (long)j * NGEMM, dst + j * 256);
            }
            __syncthreads();
        }
        return;
    }

    // consumer: permuted channel ownership
    const int s = blk_ch * 64 + (lane & 3) * 16 + (lane >> 2);
    const float CK = -0.34657359027997264f;  // -ln2/2: c = CK * c2
    if (chunk == 0) { h_out[s] = 0.f; c_out[s] = 0.f; }
    float h = 0.f, c2 = 0.f, cval = 0.f;
    float* hp = h_out + SDIM + s;
    float* cp = c_out + SDIM + s;

    __syncthreads();   // chunk 0 ready
    for (int k = 0; k < NC; ++k) {
        const u32* Ld = &lds[k & 1][0][0];
        u32 R[PF][4];
        #pragma unroll
        for (int p = 0; p < PF; ++p) {
            R[p][0] = Ld[p * 256 + lane];
            R[p][1] = Ld[p * 256 + 64 + lane];
            R[p][2] = Ld[p * 256 + 128 + lane];
            R[p][3] = Ld[p * 256 + 192 + lane];
        }
        const long tbase = tstart + (long)k * CHUNK;
        if (k < warm) {
            #pragma unroll
            for (int j = 0; j < CHUNK; ++j) {
                STEP(R[j & (PF - 1)]);
                if (j < CHUNK - PF) {
                    R[j & (PF - 1)][0] = Ld[(j + PF) * 256 + lane];
                    R[j & (PF - 1)][1] = Ld[(j + PF) * 256 + 64 + lane];
                    R[j & (PF - 1)][2] = Ld[(j + PF) * 256 + 128 + lane];
                    R[j & (PF - 1)][3] = Ld[(j + PF) * 256 + 192 + lane];
                }
            }
        } else {
            #pragma unroll
            for (int j = 0; j < CHUNK; ++j) {
                STEP(R[j & (PF - 1)]);
                hp[(tbase + j) * SDIM] = h;
                cp[(tbase + j) * SDIM] = cval;
                if (j < CHUNK - PF) {
                    R[j & (PF - 1)][0] = Ld[(j + PF) * 256 + lane];
                    R[j & (PF - 1)][1] = Ld[(j + PF) * 256 + 64 + lane];
                    R[j & (PF - 1)][2] = Ld[(j + PF) * 256 + 128 + lane];
                    R[j & (PF - 1)][3] = Ld[(j + PF) * 256 + 192 + lane];
                }
            }
        }
        __syncthreads();
    }
}

// ---------- q_t = h_n[1:] @ W_reg^T + b_reg : one wave per timestep ----------
__global__ __launch_bounds__(256) void q_kernel(const float* __restrict__ h_n,
                                                const float* __restrict__ wreg,
                                                const float* __restrict__ breg,
                                                float* __restrict__ q) {
    int gw = (blockIdx.x * blockDim.x + threadIdx.x) >> 6;  // t
    int lane = threadIdx.x & 63;
    if (gw >= T_STEPS) return;
    const float* row = h_n + (long)(gw + 1) * SDIM;
    float sum = 0.f;
    #pragma unroll
    for (int j = 0; j < 8; ++j)
        sum += row[lane + j * 64] * wreg[lane + j * 64];
    #pragma unroll
    for (int off = 32; off > 0; off >>= 1)
        sum += __shfl_down(sum, off, 64);
    if (lane == 0) q[gw] = sum + breg[0];
}

extern "C" void kernel_launch(void* const* d_in, const int* in_sizes, int n_in,
                              void* d_out, int out_size, void* d_ws, size_t ws_size,
                              hipStream_t stream) {
    const float* x     = (const float*)d_in[0];   // (16384,1024)
    const float* w_in  = (const float*)d_in[1];   // (512,4,1024)
    const float* w_rec = (const float*)d_in[2];   // (4,512)
    const float* bias  = (const float*)d_in[3];   // (4,512)
    const float* w_reg = (const float*)d_in[4];   // (1,512)
    const float* b_reg = (const float*)d_in[5];   // (1,)

    float* out = (float*)d_out;
    float* q   = out;                               // 16384
    float* h_n = out + T_STEPS;                     // 16385*512
    float* c_n = h_n + (long)(T_STEPS + 1) * SDIM;  // 16385*512

    char* ws = (char*)d_ws;
    const size_t COEF_BYTES = (size_t)T_STEPS * NGEMM * 4;   // 134217728
    const size_t XB_BYTES   = (size_t)T_STEPS * INP * 2;     // 33554432
    u32* coef = (u32*)ws;
    u16* xb   = (u16*)(ws + COEF_BYTES);
    u16* wb   = (u16*)(ws + COEF_BYTES + XB_BYTES);

    cvt_x<<<4096, 256, 0, stream>>>(x, xb, (long)T_STEPS * INP / 4);
    pack_w<<<2048, 256, 0, stream>>>(w_in, wb);
    gemm_bt<<<(T_STEPS / 256) * (NGEMM / 256), 512, 0, stream>>>(xb, wb, w_rec, bias, coef, T_STEPS, NGEMM, INP);
    lstm_scan<<<8 * NPAR, 128, 0, stream>>>(coef, h_n, c_n);
    q_kernel<<<(T_STEPS * 64) / 256, 256, 0, stream>>>(h_n, w_reg, b_reg, q);
}

// Round 15
// 153.587 us; speedup vs baseline: 1.0283x; 1.0283x over previous
//
#include <hip/hip_runtime.h>

typedef unsigned short u16;
typedef unsigned int u32;
typedef __attribute__((ext_vector_type(4))) unsigned short u16x4;
typedef __attribute__((ext_vector_type(8))) short short8;
typedef __attribute__((ext_vector_type(8))) __bf16 bf16x8;
typedef __attribute__((ext_vector_type(4))) float f32x4;

#define T_STEPS 16384
#define INP 1024
#define SDIM 512
#define NGEMM 2048   // 4 gates * 512
#define L2E 1.4426950408889634f

__device__ __forceinline__ u16 f2bf(float f) {
    unsigned u = __float_as_uint(f);
    return (u16)((u + 0x7fffu + ((u >> 16) & 1u)) >> 16);
}
__device__ __forceinline__ float bfhi(u32 d) { return __uint_as_float(d & 0xffff0000u); }
__device__ __forceinline__ float bflo(u32 d) { return __uint_as_float(d << 16); }

__device__ __forceinline__ void gload_lds16(const void* g, void* l) {
    __builtin_amdgcn_global_load_lds((const __attribute__((address_space(1))) unsigned*)g,
                                     (__attribute__((address_space(3))) unsigned*)l, 16, 0, 0);
}

// ---------- fused prep: convert x -> bf16 AND pack weight_input -> bf16 ----------
// range [0, n4x): cvt of x (float4 units). range [n4x, n4x+n4w): pack_w units.
__global__ void prep(const float* __restrict__ x, u16* __restrict__ xb,
                     const float* __restrict__ w, u16* __restrict__ wb) {
    const long n4x = (long)T_STEPS * INP / 4;   // 4194304
    const long n4w = (long)SDIM * 4 * INP / 4;  // 524288
    long i = (long)blockIdx.x * blockDim.x + threadIdx.x;
    long stride = (long)gridDim.x * blockDim.x;
    for (; i < n4x + n4w; i += stride) {
        if (i < n4x) {
            float4 v = ((const float4*)x)[i];
            u16x4 o;
            o.x = f2bf(v.x); o.y = f2bf(v.y); o.z = f2bf(v.z); o.w = f2bf(v.w);
            ((u16x4*)xb)[i] = o;
        } else {
            int id = (int)(i - n4x);
            int kv = id & 255;          // k/4
            int n  = id >> 8;           // 0..2047
            int g = n >> 9, s = n & 511;
            const float4 v = *(const float4*)(w + ((long)(s * 4 + g)) * INP + kv * 4);
            u16x4 o;
            o.x = f2bf(v.x); o.y = f2bf(v.y); o.z = f2bf(v.z); o.w = f2bf(v.w);
            *(u16x4*)(wb + (long)n * INP + kv * 4) = o;
        }
    }
}

// ---------- GEMM: 256x256, 8 waves, 4-BUF ring, R13 schedule + fine-grained waits ----------
// Iter t (read buf t%4):
//  PHASE_A: ds_read afr0,bfr0-3,afr1-3 (8) ; barrier ; [compiler lgkmcnt] ;
//           prio1 ; 16 MFMA ; prio0
//  PHASE_B: ds_read afr4-7 (4) ; vmcnt(4) ; STAGE(buf (t+3)%4, tile t+3) ;
//           barrier ; [compiler lgkmcnt] ; prio1 ; 16 MFMA ; prio0
// Change vs R13: the COARSE asm lgkmcnt(0) drains are removed — the ds_reads
// feed MFMA through SSA values, so the compiler inserts fine-grained
// lgkmcnt(N) before each first use (m97-verified behavior); first MFMA starts
// after its own operands retire, not after all 8/4 reads. Read order in
// PHASE_A puts afr0+bfr first. Rule #18 doesn't apply (no asm lgkm to hoist past).
// vmcnt FIFO (unchanged, verified): before PB(t)'s wait, outstanding = tiles
// t+1,t+2 (8 loads) -> vmcnt(4) waits EXACTLY tile t+1 (staged 2 iters ago ->
// never blocks steady-state). Stage safety: STAGE at PB(t) writes buf (t-1)%4,
// whose readers (iter t-1) retired reads before PB(t-1)'s MFMA (compiler waits
// precede use; all reads of iter t-1 retired before PA(t)'s barrier is passed
// by that wave); PA(t)+PB(t) barriers order all waves before the STAGE point.
// Tail: t=28 stages tile31; t=29 vmcnt(4) waits t30; t=30 vmcnt(0); t=31 nop.
// Swizzle (R7, conflicts=0). XCD swizzle: 512 blocks %8==0. Epilogue: permuted
// coef layout, uint4 stores (WRITE_SIZE verified exactly 131072 KB).
__global__ __launch_bounds__(512, 2) void gemm_bt(const u16* __restrict__ A,
                                                  const u16* __restrict__ B,
                                                  const float* __restrict__ wrec,
                                                  const float* __restrict__ bsv,
                                                  u32* __restrict__ coef,
                                                  int M, int N, int K) {
    __shared__ u16 sA[4][256 * 32];
    __shared__ u16 sB[4][256 * 32];
    const int tid = threadIdx.x;
    const int nbx = N >> 8;                 // 8
    const int nwg = gridDim.x;              // 512
    const int cpx = nwg >> 3;
    const int bid = ((int)blockIdx.x & 7) * cpx + ((int)blockIdx.x >> 3);
    const int bx = bid % nbx, by = bid / nbx;
    const long brow = (long)by << 8, bcol = (long)bx << 8;
    const int w = tid >> 6, lane = tid & 63;
    const int wr = w >> 2, wc = w & 3;      // 2 x 4 waves
    const int r16 = lane & 15, kq = lane >> 4;

    // staging: each wave stages rows [w*32, w*32+32) of A and B (2 gloads each)
    const int row0  = w * 32 + (lane >> 2);
    const int sslot = lane & 3;
    const int chs   = sslot ^ ((row0 >> 1) & 3);
    const u16* gA0 = A + (brow + row0) * (long)K + chs * 8;
    const u16* gA1 = gA0 + 16 * (long)K;
    const u16* gB0 = B + (bcol + row0) * (long)K + chs * 8;
    const u16* gB1 = gB0 + 16 * (long)K;
    const int dst0 = row0 * 32 + sslot * 8;
    const int dst1 = dst0 + 16 * 32;

    const int slotR = kq ^ ((r16 >> 1) & 3);
    int aoff[8], boff[4];
    #pragma unroll
    for (int m = 0; m < 8; ++m)
        aoff[m] = (wr * 128 + m * 16 + r16) * 32 + slotR * 8;
    #pragma unroll
    for (int n = 0; n < 4; ++n)
        boff[n] = (wc * 64 + n * 16 + r16) * 32 + slotR * 8;

    f32x4 acc[8][4] = {};
    bf16x8 bfr[4];

#define STAGE(BUF, koff) do { \
        gload_lds16(gA0 + (koff), &sA[BUF][dst0]); \
        gload_lds16(gA1 + (koff), &sA[BUF][dst1]); \
        gload_lds16(gB0 + (koff), &sB[BUF][dst0]); \
        gload_lds16(gB1 + (koff), &sB[BUF][dst1]); \
    } while (0)

#define PHASE_A(BUF) do { \
        bf16x8 afr[4]; \
        afr[0] = *(const bf16x8*)&sA[BUF][aoff[0]]; \
        _Pragma("unroll") for (int n_ = 0; n_ < 4; ++n_) \
            bfr[n_] = *(const bf16x8*)&sB[BUF][boff[n_]]; \
        _Pragma("unroll") for (int m_ = 1; m_ < 4; ++m_) \
            afr[m_] = *(const bf16x8*)&sA[BUF][aoff[m_]]; \
        __builtin_amdgcn_s_barrier(); \
        __builtin_amdgcn_s_setprio(1); \
        _Pragma("unroll") for (int m_ = 0; m_ < 4; ++m_) \
            _Pragma("unroll") for (int n_ = 0; n_ < 4; ++n_) \
                acc[m_][n_] = __builtin_amdgcn_mfma_f32_16x16x32_bf16(afr[m_], bfr[n_], acc[m_][n_], 0, 0, 0); \
        __builtin_amdgcn_s_setprio(0); \
    } while (0)

#define PHASE_B(BUF, SBUF, SKOFF, WAITSTR, DOSTAGE) do { \
        bf16x8 afr[4]; \
        _Pragma("unroll") for (int m_ = 0; m_ < 4; ++m_) \
            afr[m_] = *(const bf16x8*)&sA[BUF][aoff[4 + m_]]; \
        asm volatile(WAITSTR ::: "memory"); \
        if (DOSTAGE) { STAGE(SBUF, SKOFF); } \
        __builtin_amdgcn_s_barrier(); \
        __builtin_amdgcn_s_setprio(1); \
        _Pragma("unroll") for (int m_ = 0; m_ < 4; ++m_) \
            _Pragma("unroll") for (int n_ = 0; n_ < 4; ++n_) \
                acc[4 + m_][n_] = __builtin_amdgcn_mfma_f32_16x16x32_bf16(afr[m_], bfr[n_], acc[4 + m_][n_], 0, 0, 0); \
        __builtin_amdgcn_s_setprio(0); \
    } while (0)

    // prologue: tiles 0,1,2 -> bufs 0,1,2 (12 loads); wait tile 0; barrier
    STAGE(0, 0);
    STAGE(1, 32);
    STAGE(2, 64);
    asm volatile("s_waitcnt vmcnt(8)" ::: "memory");
    __builtin_amdgcn_s_barrier();

    // main: t=0..27 (x4 unroll), stage tiles 3..30 into buf (t+3)%4
    #pragma unroll 1
    for (int t = 0; t < 28; t += 4) {
        PHASE_A(0); PHASE_B(0, 3, (t + 3) * 32, "s_waitcnt vmcnt(4)", 1);
        PHASE_A(1); PHASE_B(1, 0, (t + 4) * 32, "s_waitcnt vmcnt(4)", 1);
        PHASE_A(2); PHASE_B(2, 1, (t + 5) * 32, "s_waitcnt vmcnt(4)", 1);
        PHASE_A(3); PHASE_B(3, 2, (t + 6) * 32, "s_waitcnt vmcnt(4)", 1);
    }
    PHASE_A(0); PHASE_B(0, 3, 31 * 32, "s_waitcnt vmcnt(4)", 1);   // t=28: stage tile 31
    PHASE_A(1); PHASE_B(1, 0, 0,       "s_waitcnt vmcnt(4)", 0);   // t=29: wait tile 30
    PHASE_A(2); PHASE_B(2, 0, 0,       "s_waitcnt vmcnt(0)", 0);   // t=30: wait tile 31
    PHASE_A(3); PHASE_B(3, 0, 0,       "s_waitcnt vmcnt(0)", 0);   // t=31: no-op
#undef PHASE_A
#undef PHASE_B
#undef STAGE

    // ---- epilogue: linearized coeffs, PERMUTED layout, coalesced uint4 stores ----
    const int g = (int)(bcol >> 9);                  // block-uniform gate
    float wvv[4], bvv[4];
    #pragma unroll
    for (int n = 0; n < 4; ++n) {
        long col = bcol + wc * 64 + n * 16 + r16;
        wvv[n] = wrec[col]; bvv[n] = bsv[col];
    }
    #pragma unroll
    for (int m = 0; m < 8; ++m) {
        #pragma unroll
        for (int j = 0; j < 4; ++j) {
            u32 pk[4];
            #pragma unroll
            for (int n = 0; n < 4; ++n) {
                float z0 = acc[m][n][j] + bvv[n];
                if (g == 3) {
                    float et = __builtin_amdgcn_exp2f(-2.f * L2E * z0);
                    float r = __builtin_amdgcn_rcpf(1.f + et);
                    float t = __builtin_fmaf(2.f, r, -1.f);
                    pk[n] = ((u32)f2bf(t) << 16) | f2bf((1.f - t * t) * wvv[n]);
                } else {
                    float e = __builtin_amdgcn_exp2f(-L2E * z0);
                    float r = __builtin_amdgcn_rcpf(1.f + e);
                    float kk = (g == 0) ? 1.f : ((g == 1) ? (-2.f * L2E) : 2.f);
                    float C0 = kk * r;
                    pk[n] = ((u32)f2bf(C0) << 16) | f2bf(C0 * r * e * wvv[n]);
                }
            }
            long row = brow + wr * 128 + m * 16 + kq * 4 + j;
            uint4 v4; v4.x = pk[0]; v4.y = pk[1]; v4.z = pk[2]; v4.w = pk[3];
            *(uint4*)(coef + row * NGEMM + bcol + wc * 64 + r16 * 4) = v4;
        }
    }
}

// ---------- diagonal LSTM scan, parallel-in-time ----------
// 32 time-chunks x 8 channel-groups = 256 blocks; 64-step warm-up (see R5).
// Consumer lane L owns channel s_own = blk64 + (L&3)*16 + (L>>2) to match the
// gemm epilogue's permuted coef layout (LDS position L holds that channel).
#define CHUNK 64
#define LCHUNK 512
#define NPAR (T_STEPS / LCHUNK)   // 32
#define PF 4

#define STEP(U) do { \
    float fh  = __builtin_fmaf(bflo((U)[0]), h, bfhi((U)[0])); \
    float ia  = __builtin_fmaf(bflo((U)[1]), h, bfhi((U)[1])); \
    float oo2 = __builtin_fmaf(bflo((U)[2]), h, bfhi((U)[2])); \
    float gb  = __builtin_fmaf(bflo((U)[3]), h, bfhi((U)[3])); \
    float ign = ia * gb; \
    float negoo = -0.5f * oo2; \
    c2 = __builtin_fmaf(fh, c2, ign); \
    float rt = __builtin_amdgcn_rcpf(1.f + __builtin_amdgcn_exp2f(c2)); \
    h = __builtin_fmaf(oo2, rt, negoo); \
    cval = c2 * CK; \
} while (0)

__global__ __launch_bounds__(128) void lstm_scan(const u32* __restrict__ coef,
                                                 float* __restrict__ h_out,
                                                 float* __restrict__ c_out) {
    __shared__ u32 lds[2][CHUNK][256];   // 128 KiB
    const int tid = threadIdx.x;
    const int lane = tid & 63;
    const int blk_ch = blockIdx.x & 7;
    const int chunk = blockIdx.x >> 3;
    const int warm = (chunk == 0) ? 0 : 1;
    const long tstart = (long)chunk * LCHUNK - (long)warm * CHUNK;
    const int NC = LCHUNK / CHUNK + warm;

    if (tid >= 64) {
        const u32* src = coef + tstart * NGEMM + (lane >> 4) * SDIM + blk_ch * 64 + (lane & 15) * 4;
        #pragma unroll 8
        for (int j = 0; j < CHUNK; ++j)
            gload_lds16(src + (long)j * NGEMM, &lds[0][j][0]);
        __syncthreads();
        for (int k = 0; k < NC; ++k) {
            if (k + 1 < NC) {
                const u32* s2 = src + (long)(k + 1) * CHUNK * NGEMM;
                u32* dst = &lds[(k + 1) & 1][0][0];
                #pragma unroll 8
                for (int j = 0; j < CHUNK; ++j)
                    gload_lds16(s2 + (long)j * NGEMM, dst + j * 256);
            }
            __syncthreads();
        }
        return;
    }

    // consumer: permuted channel ownership
    const int s = blk_ch * 64 + (lane & 3) * 16 + (lane >> 2);
    const float CK = -0.34657359027997264f;  // -ln2/2: c = CK * c2
    if (chunk == 0) { h_out[s] = 0.f; c_out[s] = 0.f; }
    float h = 0.f, c2 = 0.f, cval = 0.f;
    float* hp = h_out + SDIM + s;
    float* cp = c_out + SDIM + s;

    __syncthreads();   // chunk 0 ready
    for (int k = 0; k < NC; ++k) {
        const u32* Ld = &lds[k & 1][0][0];
        u32 R[PF][4];
        #pragma unroll
        for (int p = 0; p < PF; ++p) {
            R[p][0] = Ld[p * 256 + lane];
            R[p][1] = Ld[p * 256 + 64 + lane];
            R[p][2] = Ld[p * 256 + 128 + lane];
            R[p][3] = Ld[p * 256 + 192 + lane];
        }
        const long tbase = tstart + (long)k * CHUNK;
        if (k < warm) {
            #pragma unroll
            for (int j = 0; j < CHUNK; ++j) {
                STEP(R[j & (PF - 1)]);
                if (j < CHUNK - PF) {
                    R[j & (PF - 1)][0] = Ld[(j + PF) * 256 + lane];
                    R[j & (PF - 1)][1] = Ld[(j + PF) * 256 + 64 + lane];
                    R[j & (PF - 1)][2] = Ld[(j + PF) * 256 + 128 + lane];
                    R[j & (PF - 1)][3] = Ld[(j + PF) * 256 + 192 + lane];
                }
            }
        } else {
            #pragma unroll
            for (int j = 0; j < CHUNK; ++j) {
                STEP(R[j & (PF - 1)]);
                hp[(tbase + j) * SDIM] = h;
                cp[(tbase + j) * SDIM] = cval;
                if (j < CHUNK - PF) {
                    R[j & (PF - 1)][0] = Ld[(j + PF) * 256 + lane];
                    R[j & (PF - 1)][1] = Ld[(j + PF) * 256 + 64 + lane];
                    R[j & (PF - 1)][2] = Ld[(j + PF) * 256 + 128 + lane];
                    R[j & (PF - 1)][3] = Ld[(j + PF) * 256 + 192 + lane];
                }
            }
        }
        __syncthreads();
    }
}

// ---------- q_t = h_n[1:] @ W_reg^T + b_reg : one wave per timestep ----------
__global__ __launch_bounds__(256) void q_kernel(const float* __restrict__ h_n,
                                                const float* __restrict__ wreg,
                                                const float* __restrict__ breg,
                                                float* __restrict__ q) {
    int gw = (blockIdx.x * blockDim.x + threadIdx.x) >> 6;  // t
    int lane = threadIdx.x & 63;
    if (gw >= T_STEPS) return;
    const float* row = h_n + (long)(gw + 1) * SDIM;
    float sum = 0.f;
    #pragma unroll
    for (int j = 0; j < 8; ++j)
        sum += row[lane + j * 64] * wreg[lane + j * 64];
    #pragma unroll
    for (int off = 32; off > 0; off >>= 1)
        sum += __shfl_down(sum, off, 64);
    if (lane == 0) q[gw] = sum + breg[0];
}

extern "C" void kernel_launch(void* const* d_in, const int* in_sizes, int n_in,
                              void* d_out, int out_size, void* d_ws, size_t ws_size,
                              hipStream_t stream) {
    const float* x     = (const float*)d_in[0];   // (16384,1024)
    const float* w_in  = (const float*)d_in[1];   // (512,4,1024)
    const float* w_rec = (const float*)d_in[2];   // (4,512)
    const float* bias  = (const float*)d_in[3];   // (4,512)
    const float* w_reg = (const float*)d_in[4];   // (1,512)
    const float* b_reg = (const float*)d_in[5];   // (1,)

    float* out = (float*)d_out;
    float* q   = out;                               // 16384
    float* h_n = out + T_STEPS;                     // 16385*512
    float* c_n = h_n + (long)(T_STEPS + 1) * SDIM;  // 16385*512

    char* ws = (char*)d_ws;
    const size_t COEF_BYTES = (size_t)T_STEPS * NGEMM * 4;   // 134217728
    const size_t XB_BYTES   = (size_t)T_STEPS * INP * 2;     // 33554432
    u32* coef = (u32*)ws;
    u16* xb   = (u16*)(ws + COEF_BYTES);
    u16* wb   = (u16*)(ws + COEF_BYTES + XB_BYTES);

    prep<<<4608, 256, 0, stream>>>(x, xb, w_in, wb);
    gemm_bt<<<(T_STEPS / 256) * (NGEMM / 256), 512, 0, stream>>>(xb, wb, w_rec, bias, coef, T_STEPS, NGEMM, INP);
    lstm_scan<<<8 * NPAR, 128, 0, stream>>>(coef, h_n, c_n);
    q_kernel<<<(T_STEPS * 64) / 256, 256, 0, stream>>>(h_n, w_reg, b_reg, q);
}

// Round 16
// 147.772 us; speedup vs baseline: 1.0688x; 1.0394x over previous
//
#include <hip/hip_runtime.h>

typedef unsigned short u16;
typedef unsigned int u32;
typedef __attribute__((ext_vector_type(4))) unsigned short u16x4;
typedef __attribute__((ext_vector_type(8))) short short8;
typedef __attribute__((ext_vector_type(8))) __bf16 bf16x8;
typedef __attribute__((ext_vector_type(4))) float f32x4;

#define T_STEPS 16384
#define INP 1024
#define SDIM 512
#define NGEMM 2048   // 4 gates * 512
#define L2E 1.4426950408889634f

__device__ __forceinline__ u16 f2bf(float f) {
    unsigned u = __float_as_uint(f);
    return (u16)((u + 0x7fffu + ((u >> 16) & 1u)) >> 16);
}
__device__ __forceinline__ float bfhi(u32 d) { return __uint_as_float(d & 0xffff0000u); }
__device__ __forceinline__ float bflo(u32 d) { return __uint_as_float(d << 16); }

__device__ __forceinline__ void gload_lds16(const void* g, void* l) {
    __builtin_amdgcn_global_load_lds((const __attribute__((address_space(1))) unsigned*)g,
                                     (__attribute__((address_space(3))) unsigned*)l, 16, 0, 0);
}

// ---------- convert x (T,1024) fp32 -> bf16 ----------
__global__ void cvt_x(const float* __restrict__ x, u16* __restrict__ xb, long n4) {
    long i = (long)blockIdx.x * blockDim.x + threadIdx.x;
    long stride = (long)gridDim.x * blockDim.x;
    for (; i < n4; i += stride) {
        float4 v = ((const float4*)x)[i];
        u16x4 o;
        o.x = f2bf(v.x); o.y = f2bf(v.y); o.z = f2bf(v.z); o.w = f2bf(v.w);
        ((u16x4*)xb)[i] = o;
    }
}

// ---------- pack weight_input (512,4,1024) fp32 -> bf16 (2048,1024) with n = g*512+s ----------
__global__ void pack_w(const float* __restrict__ w, u16* __restrict__ wb) {
    int id = blockIdx.x * blockDim.x + threadIdx.x;
    int kv = id & 255;          // k/4
    int n  = id >> 8;           // 0..2047
    int g = n >> 9, s = n & 511;
    const float4 v = *(const float4*)(w + ((long)(s * 4 + g)) * INP + kv * 4);
    u16x4 o;
    o.x = f2bf(v.x); o.y = f2bf(v.y); o.z = f2bf(v.z); o.w = f2bf(v.w);
    *(u16x4*)(wb + (long)n * INP + kv * 4) = o;
}

// ---------- GEMM: 256x256, 8 waves, 4-BUF ring (R15 structure, measured 89-91us) ----------
// Iter t (read buf t%4):
//  PHASE_A: ds_read afr0,bfr0-3,afr1-3 (8) ; barrier ; [compiler lgkmcnt] ;
//           prio1 ; 16 MFMA ; prio0
//  PHASE_B: ds_read afr4-7 (4) ; vmcnt(4) ; STAGE(buf (t+3)%4, tile t+3) ;
//           barrier ; [compiler lgkmcnt] ; prio1 ; 16 MFMA ; prio0
// vmcnt FIFO (verified): before PB(t)'s wait, outstanding = tiles t+1,t+2 (8
// loads) -> vmcnt(4) waits EXACTLY tile t+1 (staged 2 iters ago -> never blocks
// steady-state). Stage safety: STAGE at PB(t) writes buf (t-1)%4, whose readers
// (iter t-1) retired reads before their MFMA use (compiler waits precede use);
// PA(t)+PB(t) barriers order all waves before the STAGE point. Tail: t=28
// stages tile31; t=29 vmcnt(4) waits t30; t=30 vmcnt(0); t=31 nop.
// Swizzle (R7, conflicts=0). XCD swizzle: 512 blocks %8==0. Epilogue: permuted
// coef layout, uint4 stores (WRITE_SIZE verified exactly 131072 KB).
__global__ __launch_bounds__(512, 2) void gemm_bt(const u16* __restrict__ A,
                                                  const u16* __restrict__ B,
                                                  const float* __restrict__ wrec,
                                                  const float* __restrict__ bsv,
                                                  u32* __restrict__ coef,
                                                  int M, int N, int K) {
    __shared__ u16 sA[4][256 * 32];
    __shared__ u16 sB[4][256 * 32];
    const int tid = threadIdx.x;
    const int nbx = N >> 8;                 // 8
    const int nwg = gridDim.x;              // 512
    const int cpx = nwg >> 3;
    const int bid = ((int)blockIdx.x & 7) * cpx + ((int)blockIdx.x >> 3);
    const int bx = bid % nbx, by = bid / nbx;
    const long brow = (long)by << 8, bcol = (long)bx << 8;
    const int w = tid >> 6, lane = tid & 63;
    const int wr = w >> 2, wc = w & 3;      // 2 x 4 waves
    const int r16 = lane & 15, kq = lane >> 4;

    // staging: each wave stages rows [w*32, w*32+32) of A and B (2 gloads each)
    const int row0  = w * 32 + (lane >> 2);
    const int sslot = lane & 3;
    const int chs   = sslot ^ ((row0 >> 1) & 3);
    const u16* gA0 = A + (brow + row0) * (long)K + chs * 8;
    const u16* gA1 = gA0 + 16 * (long)K;
    const u16* gB0 = B + (bcol + row0) * (long)K + chs * 8;
    const u16* gB1 = gB0 + 16 * (long)K;
    const int dst0 = row0 * 32 + sslot * 8;
    const int dst1 = dst0 + 16 * 32;

    const int slotR = kq ^ ((r16 >> 1) & 3);
    int aoff[8], boff[4];
    #pragma unroll
    for (int m = 0; m < 8; ++m)
        aoff[m] = (wr * 128 + m * 16 + r16) * 32 + slotR * 8;
    #pragma unroll
    for (int n = 0; n < 4; ++n)
        boff[n] = (wc * 64 + n * 16 + r16) * 32 + slotR * 8;

    f32x4 acc[8][4] = {};
    bf16x8 bfr[4];

#define STAGE(BUF, koff) do { \
        gload_lds16(gA0 + (koff), &sA[BUF][dst0]); \
        gload_lds16(gA1 + (koff), &sA[BUF][dst1]); \
        gload_lds16(gB0 + (koff), &sB[BUF][dst0]); \
        gload_lds16(gB1 + (koff), &sB[BUF][dst1]); \
    } while (0)

#define PHASE_A(BUF) do { \
        bf16x8 afr[4]; \
        afr[0] = *(const bf16x8*)&sA[BUF][aoff[0]]; \
        _Pragma("unroll") for (int n_ = 0; n_ < 4; ++n_) \
            bfr[n_] = *(const bf16x8*)&sB[BUF][boff[n_]]; \
        _Pragma("unroll") for (int m_ = 1; m_ < 4; ++m_) \
            afr[m_] = *(const bf16x8*)&sA[BUF][aoff[m_]]; \
        __builtin_amdgcn_s_barrier(); \
        __builtin_amdgcn_s_setprio(1); \
        _Pragma("unroll") for (int m_ = 0; m_ < 4; ++m_) \
            _Pragma("unroll") for (int n_ = 0; n_ < 4; ++n_) \
                acc[m_][n_] = __builtin_amdgcn_mfma_f32_16x16x32_bf16(afr[m_], bfr[n_], acc[m_][n_], 0, 0, 0); \
        __builtin_amdgcn_s_setprio(0); \
    } while (0)

#define PHASE_B(BUF, SBUF, SKOFF, WAITSTR, DOSTAGE) do { \
        bf16x8 afr[4]; \
        _Pragma("unroll") for (int m_ = 0; m_ < 4; ++m_) \
            afr[m_] = *(const bf16x8*)&sA[BUF][aoff[4 + m_]]; \
        asm volatile(WAITSTR ::: "memory"); \
        if (DOSTAGE) { STAGE(SBUF, SKOFF); } \
        __builtin_amdgcn_s_barrier(); \
        __builtin_amdgcn_s_setprio(1); \
        _Pragma("unroll") for (int m_ = 0; m_ < 4; ++m_) \
            _Pragma("unroll") for (int n_ = 0; n_ < 4; ++n_) \
                acc[4 + m_][n_] = __builtin_amdgcn_mfma_f32_16x16x32_bf16(afr[m_], bfr[n_], acc[4 + m_][n_], 0, 0, 0); \
        __builtin_amdgcn_s_setprio(0); \
    } while (0)

    // prologue: tiles 0,1,2 -> bufs 0,1,2 (12 loads); wait tile 0; barrier
    STAGE(0, 0);
    STAGE(1, 32);
    STAGE(2, 64);
    asm volatile("s_waitcnt vmcnt(8)" ::: "memory");
    __builtin_amdgcn_s_barrier();

    // main: t=0..27 (x4 unroll), stage tiles 3..30 into buf (t+3)%4
    #pragma unroll 1
    for (int t = 0; t < 28; t += 4) {
        PHASE_A(0); PHASE_B(0, 3, (t + 3) * 32, "s_waitcnt vmcnt(4)", 1);
        PHASE_A(1); PHASE_B(1, 0, (t + 4) * 32, "s_waitcnt vmcnt(4)", 1);
        PHASE_A(2); PHASE_B(2, 1, (t + 5) * 32, "s_waitcnt vmcnt(4)", 1);
        PHASE_A(3); PHASE_B(3, 2, (t + 6) * 32, "s_waitcnt vmcnt(4)", 1);
    }
    PHASE_A(0); PHASE_B(0, 3, 31 * 32, "s_waitcnt vmcnt(4)", 1);   // t=28: stage tile 31
    PHASE_A(1); PHASE_B(1, 0, 0,       "s_waitcnt vmcnt(4)", 0);   // t=29: wait tile 30
    PHASE_A(2); PHASE_B(2, 0, 0,       "s_waitcnt vmcnt(0)", 0);   // t=30: wait tile 31
    PHASE_A(3); PHASE_B(3, 0, 0,       "s_waitcnt vmcnt(0)", 0);   // t=31: no-op
#undef PHASE_A
#undef PHASE_B
#undef STAGE

    // ---- epilogue: linearized coeffs, PERMUTED layout, coalesced uint4 stores ----
    const int g = (int)(bcol >> 9);                  // block-uniform gate
    float wvv[4], bvv[4];
    #pragma unroll
    for (int n = 0; n < 4; ++n) {
        long col = bcol + wc * 64 + n * 16 + r16;
        wvv[n] = wrec[col]; bvv[n] = bsv[col];
    }
    #pragma unroll
    for (int m = 0; m < 8; ++m) {
        #pragma unroll
        for (int j = 0; j < 4; ++j) {
            u32 pk[4];
            #pragma unroll
            for (int n = 0; n < 4; ++n) {
                float z0 = acc[m][n][j] + bvv[n];
                if (g == 3) {
                    float et = __builtin_amdgcn_exp2f(-2.f * L2E * z0);
                    float r = __builtin_amdgcn_rcpf(1.f + et);
                    float t = __builtin_fmaf(2.f, r, -1.f);
                    pk[n] = ((u32)f2bf(t) << 16) | f2bf((1.f - t * t) * wvv[n]);
                } else {
                    float e = __builtin_amdgcn_exp2f(-L2E * z0);
                    float r = __builtin_amdgcn_rcpf(1.f + e);
                    float kk = (g == 0) ? 1.f : ((g == 1) ? (-2.f * L2E) : 2.f);
                    float C0 = kk * r;
                    pk[n] = ((u32)f2bf(C0) << 16) | f2bf(C0 * r * e * wvv[n]);
                }
            }
            long row = brow + wr * 128 + m * 16 + kq * 4 + j;
            uint4 v4; v4.x = pk[0]; v4.y = pk[1]; v4.z = pk[2]; v4.w = pk[3];
            *(uint4*)(coef + row * NGEMM + bcol + wc * 64 + r16 * 4) = v4;
        }
    }
}

// ---------- diagonal LSTM scan, parallel-in-time (2x parallelism vs R13) ----------
// 64 time-chunks x 8 channel-groups = 512 blocks; LCHUNK=256 with 64-step
// warm-up (2 chunks of 32; forgetting argument unchanged, R5). LDS ring
// 2 x 32 steps x 1KB = 64 KiB -> 2 blocks/CU so all 512 blocks co-resident:
// serial length per block 320 steps (~19us) vs R13's 576 (~35us). Consumer
// lane L owns channel s_own = blk64 + (L&3)*16 + (L>>2) (permuted coef layout).
#define CHUNK 32
#define LCHUNK 256
#define NPAR (T_STEPS / LCHUNK)   // 64
#define WARMCH 2                  // warm-up chunks (64 steps)
#define PF 4

#define STEP(U) do { \
    float fh  = __builtin_fmaf(bflo((U)[0]), h, bfhi((U)[0])); \
    float ia  = __builtin_fmaf(bflo((U)[1]), h, bfhi((U)[1])); \
    float oo2 = __builtin_fmaf(bflo((U)[2]), h, bfhi((U)[2])); \
    float gb  = __builtin_fmaf(bflo((U)[3]), h, bfhi((U)[3])); \
    float ign = ia * gb; \
    float negoo = -0.5f * oo2; \
    c2 = __builtin_fmaf(fh, c2, ign); \
    float rt = __builtin_amdgcn_rcpf(1.f + __builtin_amdgcn_exp2f(c2)); \
    h = __builtin_fmaf(oo2, rt, negoo); \
    cval = c2 * CK; \
} while (0)

__global__ __launch_bounds__(128) void lstm_scan(const u32* __restrict__ coef,
                                                 float* __restrict__ h_out,
                                                 float* __restrict__ c_out) {
    __shared__ u32 lds[2][CHUNK][256];   // 64 KiB -> 2 blocks/CU
    const int tid = threadIdx.x;
    const int lane = tid & 63;
    const int blk_ch = blockIdx.x & 7;
    const int chunk = blockIdx.x >> 3;
    const int warm = (chunk == 0) ? 0 : WARMCH;
    const long tstart = (long)chunk * LCHUNK - (long)warm * CHUNK;
    const int NC = LCHUNK / CHUNK + warm;       // 8 or 10

    if (tid >= 64) {
        // producer: lane L fetches gate L>>4, 16B chunk (L&15) of this group's 64 channels
        const u32* src = coef + tstart * NGEMM + (lane >> 4) * SDIM + blk_ch * 64 + (lane & 15) * 4;
        #pragma unroll 8
        for (int j = 0; j < CHUNK; ++j)
            gload_lds16(src + (long)j * NGEMM, &lds[0][j][0]);
        __syncthreads();
        for (int k = 0; k < NC; ++k) {
            if (k + 1 < NC) {
                const u32* s2 = src + (long)(k + 1) * CHUNK * NGEMM;
                u32* dst = &lds[(k + 1) & 1][0][0];
                #pragma unroll 8
                for (int j = 0; j < CHUNK; ++j)
                    gload_lds16(s2 + (long)j * NGEMM, dst + j * 256);
            }
            __syncthreads();
        }
        return;
    }

    // consumer: permuted channel ownership
    const int s = blk_ch * 64 + (lane & 3) * 16 + (lane >> 2);
    const float CK = -0.34657359027997264f;  // -ln2/2: c = CK * c2
    if (chunk == 0) { h_out[s] = 0.f; c_out[s] = 0.f; }
    float h = 0.f, c2 = 0.f, cval = 0.f;
    float* hp = h_out + SDIM + s;
    float* cp = c_out + SDIM + s;

    __syncthreads();   // chunk 0 ready
    for (int k = 0; k < NC; ++k) {
        const u32* Ld = &lds[k & 1][0][0];
        u32 R[PF][4];
        #pragma unroll
        for (int p = 0; p < PF; ++p) {
            R[p][0] = Ld[p * 256 + lane];
            R[p][1] = Ld[p * 256 + 64 + lane];
            R[p][2] = Ld[p * 256 + 128 + lane];
            R[p][3] = Ld[p * 256 + 192 + lane];
        }
        const long tbase = tstart + (long)k * CHUNK;
        if (k < warm) {
            // warm-up: evolve state, no stores
            #pragma unroll
            for (int j = 0; j < CHUNK; ++j) {
                STEP(R[j & (PF - 1)]);
                if (j < CHUNK - PF) {
                    R[j & (PF - 1)][0] = Ld[(j + PF) * 256 + lane];
                    R[j & (PF - 1)][1] = Ld[(j + PF) * 256 + 64 + lane];
                    R[j & (PF - 1)][2] = Ld[(j + PF) * 256 + 128 + lane];
                    R[j & (PF - 1)][3] = Ld[(j + PF) * 256 + 192 + lane];
                }
            }
        } else {
            #pragma unroll
            for (int j = 0; j < CHUNK; ++j) {
                STEP(R[j & (PF - 1)]);
                hp[(tbase + j) * SDIM] = h;
                cp[(tbase + j) * SDIM] = cval;
                if (j < CHUNK - PF) {
                    R[j & (PF - 1)][0] = Ld[(j + PF) * 256 + lane];
                    R[j & (PF - 1)][1] = Ld[(j + PF) * 256 + 64 + lane];
                    R[j & (PF - 1)][2] = Ld[(j + PF) * 256 + 128 + lane];
                    R[j & (PF - 1)][3] = Ld[(j + PF) * 256 + 192 + lane];
                }
            }
        }
        __syncthreads();
    }
}

// ---------- q_t = h_n[1:] @ W_reg^T + b_reg : one wave per timestep ----------
__global__ __launch_bounds__(256) void q_kernel(const float* __restrict__ h_n,
                                                const float* __restrict__ wreg,
                                                const float* __restrict__ breg,
                                                float* __restrict__ q) {
    int gw = (blockIdx.x * blockDim.x + threadIdx.x) >> 6;  // t
    int lane = threadIdx.x & 63;
    if (gw >= T_STEPS) return;
    const float* row = h_n + (long)(gw + 1) * SDIM;
    float sum = 0.f;
    #pragma unroll
    for (int j = 0; j < 8; ++j)
        sum += row[lane + j * 64] * wreg[lane + j * 64];
    #pragma unroll
    for (int off = 32; off > 0; off >>= 1)
        sum += __shfl_down(sum, off, 64);
    if (lane == 0) q[gw] = sum + breg[0];
}

extern "C" void kernel_launch(void* const* d_in, const int* in_sizes, int n_in,
                              void* d_out, int out_size, void* d_ws, size_t ws_size,
                              hipStream_t stream) {
    const float* x     = (const float*)d_in[0];   // (16384,1024)
    const float* w_in  = (const float*)d_in[1];   // (512,4,1024)
    const float* w_rec = (const float*)d_in[2];   // (4,512)
    const float* bias  = (const float*)d_in[3];   // (4,512)
    const float* w_reg = (const float*)d_in[4];   // (1,512)
    const float* b_reg = (const float*)d_in[5];   // (1,)

    float* out = (float*)d_out;
    float* q   = out;                               // 16384
    float* h_n = out + T_STEPS;                     // 16385*512
    float* c_n = h_n + (long)(T_STEPS + 1) * SDIM;  // 16385*512

    char* ws = (char*)d_ws;
    const size_t COEF_BYTES = (size_t)T_STEPS * NGEMM * 4;   // 134217728
    const size_t XB_BYTES   = (size_t)T_STEPS * INP * 2;     // 33554432
    u32* coef = (u32*)ws;
    u16* xb   = (u16*)(ws + COEF_BYTES);
    u16* wb   = (u16*)(ws + COEF_BYTES + XB_BYTES);

    cvt_x<<<4096, 256, 0, stream>>>(x, xb, (long)T_STEPS * INP / 4);
    pack_w<<<2048, 256, 0, stream>>>(w_in, wb);
    gemm_bt<<<(T_STEPS / 256) * (NGEMM / 256), 512, 0, stream>>>(xb, wb, w_rec, bias, coef, T_STEPS, NGEMM, INP);
    lstm_scan<<<8 * NPAR, 128, 0, stream>>>(coef, h_n, c_n);
    q_kernel<<<(T_STEPS * 64) / 256, 256, 0, stream>>>(h_n, w_reg, b_reg, q);
}

// Round 17
// 144.955 us; speedup vs baseline: 1.0896x; 1.0194x over previous
//
#include <hip/hip_runtime.h>

typedef unsigned short u16;
typedef unsigned int u32;
typedef __attribute__((ext_vector_type(4))) unsigned short u16x4;
typedef __attribute__((ext_vector_type(8))) short short8;
typedef __attribute__((ext_vector_type(8))) __bf16 bf16x8;
typedef __attribute__((ext_vector_type(4))) float f32x4;

#define T_STEPS 16384
#define INP 1024
#define SDIM 512
#define NGEMM 2048   // 4 gates * 512
#define L2E 1.4426950408889634f

__device__ __forceinline__ u16 f2bf(float f) {
    unsigned u = __float_as_uint(f);
    return (u16)((u + 0x7fffu + ((u >> 16) & 1u)) >> 16);
}
__device__ __forceinline__ float bfhi(u32 d) { return __uint_as_float(d & 0xffff0000u); }
__device__ __forceinline__ float bflo(u32 d) { return __uint_as_float(d << 16); }

__device__ __forceinline__ void gload_lds16(const void* g, void* l) {
    __builtin_amdgcn_global_load_lds((const __attribute__((address_space(1))) unsigned*)g,
                                     (__attribute__((address_space(3))) unsigned*)l, 16, 0, 0);
}

// ---------- convert x (T,1024) fp32 -> bf16 ----------
__global__ void cvt_x(const float* __restrict__ x, u16* __restrict__ xb, long n4) {
    long i = (long)blockIdx.x * blockDim.x + threadIdx.x;
    long stride = (long)gridDim.x * blockDim.x;
    for (; i < n4; i += stride) {
        float4 v = ((const float4*)x)[i];
        u16x4 o;
        o.x = f2bf(v.x); o.y = f2bf(v.y); o.z = f2bf(v.z); o.w = f2bf(v.w);
        ((u16x4*)xb)[i] = o;
    }
}

// ---------- pack weight_input (512,4,1024) fp32 -> bf16 (2048,1024) with n = g*512+s ----------
__global__ void pack_w(const float* __restrict__ w, u16* __restrict__ wb) {
    int id = blockIdx.x * blockDim.x + threadIdx.x;
    int kv = id & 255;          // k/4
    int n  = id >> 8;           // 0..2047
    int g = n >> 9, s = n & 511;
    const float4 v = *(const float4*)(w + ((long)(s * 4 + g)) * INP + kv * 4);
    u16x4 o;
    o.x = f2bf(v.x); o.y = f2bf(v.y); o.z = f2bf(v.z); o.w = f2bf(v.w);
    *(u16x4*)(wb + (long)n * INP + kv * 4) = o;
}

// ---------- GEMM: 256x256, 8 waves, 5-BUF ring, ONE barrier per K-tile ----------
// Iter t (read buf t%5): ds_read all 12 frags (afr0,bfr0-3,afr1-7) ; vmcnt(4) ;
//   STAGE(buf (t+3)%5, tile t+3) ; barrier ; [compiler lgkm] ; prio1 ; 32 MFMA ; prio0
// Reads stay PRE-barrier (issued in prev iter's MFMA shadow) — NOT R14's
// post-barrier structure that regressed.
// Why nbuf=5: stage target (t+3)%5 == (t-2)%5 was last READ at iter t-2.
// Any wave W that passed iter t-1's barrier has, in program order, executed
// its iter t-2 MFMA burst; the compiler's lgkmcnt waits before those MFMAs
// force W's iter t-2 ds_reads RETIRED. The STAGE at iter t is issued after
// the staging wave passed iter t-1's barrier => all waves' reads of the
// target buf are retired before the DMA lands. With nbuf=4 the target is the
// buf read at iter t-1 (not yet retirement-guaranteed) — that's why R13/R15
// needed 2 barriers. Same-wave: its own t-2 reads retired before its t-2 MFMA.
// vmcnt FIFO (4 loads/iter): prologue stages tiles 0,1,2 (12 loads), vmcnt(8)
// waits tile 0. Steady: before iter t's wait, outstanding = tiles t+1,t+2 (8)
// -> vmcnt(4) waits EXACTLY tile t+1 (staged 2 iters ago -> never blocks).
// Tail: t=28 stages tile 31; t=29 vmcnt(4) waits 30; t=30 vmcnt(0) waits 31.
// LDS: 5 x (16K+16K) = 163840 B = the full 160 KiB pool (1 block/CU, as now).
// Swizzle (R7, conflicts=0). XCD swizzle: 512 blocks %8==0. Epilogue: permuted
// coef layout, uint4 stores (WRITE_SIZE verified exactly 131072 KB).
__global__ __launch_bounds__(512, 2) void gemm_bt(const u16* __restrict__ A,
                                                  const u16* __restrict__ B,
                                                  const float* __restrict__ wrec,
                                                  const float* __restrict__ bsv,
                                                  u32* __restrict__ coef,
                                                  int M, int N, int K) {
    __shared__ u16 sA[5][256 * 32];
    __shared__ u16 sB[5][256 * 32];
    const int tid = threadIdx.x;
    const int nbx = N >> 8;                 // 8
    const int nwg = gridDim.x;              // 512
    const int cpx = nwg >> 3;
    const int bid = ((int)blockIdx.x & 7) * cpx + ((int)blockIdx.x >> 3);
    const int bx = bid % nbx, by = bid / nbx;
    const long brow = (long)by << 8, bcol = (long)bx << 8;
    const int w = tid >> 6, lane = tid & 63;
    const int wr = w >> 2, wc = w & 3;      // 2 x 4 waves
    const int r16 = lane & 15, kq = lane >> 4;

    // staging: each wave stages rows [w*32, w*32+32) of A and B (2 gloads each)
    const int row0  = w * 32 + (lane >> 2);
    const int sslot = lane & 3;
    const int chs   = sslot ^ ((row0 >> 1) & 3);
    const u16* gA0 = A + (brow + row0) * (long)K + chs * 8;
    const u16* gA1 = gA0 + 16 * (long)K;
    const u16* gB0 = B + (bcol + row0) * (long)K + chs * 8;
    const u16* gB1 = gB0 + 16 * (long)K;
    const int dst0 = row0 * 32 + sslot * 8;
    const int dst1 = dst0 + 16 * 32;

    const int slotR = kq ^ ((r16 >> 1) & 3);
    int aoff[8], boff[4];
    #pragma unroll
    for (int m = 0; m < 8; ++m)
        aoff[m] = (wr * 128 + m * 16 + r16) * 32 + slotR * 8;
    #pragma unroll
    for (int n = 0; n < 4; ++n)
        boff[n] = (wc * 64 + n * 16 + r16) * 32 + slotR * 8;

    f32x4 acc[8][4] = {};

#define STAGE(BUF, koff) do { \
        gload_lds16(gA0 + (koff), &sA[BUF][dst0]); \
        gload_lds16(gA1 + (koff), &sA[BUF][dst1]); \
        gload_lds16(gB0 + (koff), &sB[BUF][dst0]); \
        gload_lds16(gB1 + (koff), &sB[BUF][dst1]); \
    } while (0)

#define ITER(BUF, SBUF, SKOFF, WAITSTR, DOSTAGE) do { \
        bf16x8 afr[8], bfr[4]; \
        afr[0] = *(const bf16x8*)&sA[BUF][aoff[0]]; \
        _Pragma("unroll") for (int n_ = 0; n_ < 4; ++n_) \
            bfr[n_] = *(const bf16x8*)&sB[BUF][boff[n_]]; \
        _Pragma("unroll") for (int m_ = 1; m_ < 8; ++m_) \
            afr[m_] = *(const bf16x8*)&sA[BUF][aoff[m_]]; \
        asm volatile(WAITSTR ::: "memory"); \
        if (DOSTAGE) { STAGE(SBUF, SKOFF); } \
        __builtin_amdgcn_s_barrier(); \
        __builtin_amdgcn_s_setprio(1); \
        _Pragma("unroll") for (int m_ = 0; m_ < 8; ++m_) \
            _Pragma("unroll") for (int n_ = 0; n_ < 4; ++n_) \
                acc[m_][n_] = __builtin_amdgcn_mfma_f32_16x16x32_bf16(afr[m_], bfr[n_], acc[m_][n_], 0, 0, 0); \
        __builtin_amdgcn_s_setprio(0); \
    } while (0)

    // prologue: tiles 0,1,2 -> bufs 0,1,2 (12 loads); wait tile 0; barrier
    STAGE(0, 0);
    STAGE(1, 32);
    STAGE(2, 64);
    asm volatile("s_waitcnt vmcnt(8)" ::: "memory");
    __builtin_amdgcn_s_barrier();

    // main: t=0..24 (x5 unroll), stage tiles 3..27 into buf (t+3)%5
    #pragma unroll 1
    for (int t = 0; t < 25; t += 5) {
        ITER(0, 3, (t + 3) * 32, "s_waitcnt vmcnt(4)", 1);
        ITER(1, 4, (t + 4) * 32, "s_waitcnt vmcnt(4)", 1);
        ITER(2, 0, (t + 5) * 32, "s_waitcnt vmcnt(4)", 1);
        ITER(3, 1, (t + 6) * 32, "s_waitcnt vmcnt(4)", 1);
        ITER(4, 2, (t + 7) * 32, "s_waitcnt vmcnt(4)", 1);
    }
    ITER(0, 3, 28 * 32, "s_waitcnt vmcnt(4)", 1);   // t=25: stage tile 28
    ITER(1, 4, 29 * 32, "s_waitcnt vmcnt(4)", 1);   // t=26: stage tile 29
    ITER(2, 0, 30 * 32, "s_waitcnt vmcnt(4)", 1);   // t=27: stage tile 30 (buf0 read at t=25 ✓)
    ITER(3, 1, 31 * 32, "s_waitcnt vmcnt(4)", 1);   // t=28: stage tile 31 (buf1 read at t=26 ✓)
    ITER(4, 0, 0,       "s_waitcnt vmcnt(4)", 0);   // t=29: wait tile 30
    ITER(0, 0, 0,       "s_waitcnt vmcnt(0)", 0);   // t=30: wait tile 31
    ITER(1, 0, 0,       "s_waitcnt vmcnt(0)", 0);   // t=31: no-op
#undef ITER
#undef STAGE

    // ---- epilogue: linearized coeffs, PERMUTED layout, coalesced uint4 stores ----
    const int g = (int)(bcol >> 9);                  // block-uniform gate
    float wvv[4], bvv[4];
    #pragma unroll
    for (int n = 0; n < 4; ++n) {
        long col = bcol + wc * 64 + n * 16 + r16;
        wvv[n] = wrec[col]; bvv[n] = bsv[col];
    }
    #pragma unroll
    for (int m = 0; m < 8; ++m) {
        #pragma unroll
        for (int j = 0; j < 4; ++j) {
            u32 pk[4];
            #pragma unroll
            for (int n = 0; n < 4; ++n) {
                float z0 = acc[m][n][j] + bvv[n];
                if (g == 3) {
                    float et = __builtin_amdgcn_exp2f(-2.f * L2E * z0);
                    float r = __builtin_amdgcn_rcpf(1.f + et);
                    float t = __builtin_fmaf(2.f, r, -1.f);
                    pk[n] = ((u32)f2bf(t) << 16) | f2bf((1.f - t * t) * wvv[n]);
                } else {
                    float e = __builtin_amdgcn_exp2f(-L2E * z0);
                    float r = __builtin_amdgcn_rcpf(1.f + e);
                    float kk = (g == 0) ? 1.f : ((g == 1) ? (-2.f * L2E) : 2.f);
                    float C0 = kk * r;
                    pk[n] = ((u32)f2bf(C0) << 16) | f2bf(C0 * r * e * wvv[n]);
                }
            }
            long row = brow + wr * 128 + m * 16 + kq * 4 + j;
            uint4 v4; v4.x = pk[0]; v4.y = pk[1]; v4.z = pk[2]; v4.w = pk[3];
            *(uint4*)(coef + row * NGEMM + bcol + wc * 64 + r16 * 4) = v4;
        }
    }
}

// ---------- diagonal LSTM scan, parallel-in-time (R16: 64 chunks x 8 groups) ----------
// LCHUNK=256 with 64-step warm-up (2 chunks of 32); LDS ring 2x32x1KB = 64KiB
// -> 2 blocks/CU, all 512 blocks co-resident; serial length 320 steps.
// Consumer lane L owns channel s_own = blk64 + (L&3)*16 + (L>>2) (permuted coef).
#define CHUNK 32
#define LCHUNK 256
#define NPAR (T_STEPS / LCHUNK)   // 64
#define WARMCH 2                  // warm-up chunks (64 steps)
#define PF 4

#define STEP(U) do { \
    float fh  = __builtin_fmaf(bflo((U)[0]), h, bfhi((U)[0])); \
    float ia  = __builtin_fmaf(bflo((U)[1]), h, bfhi((U)[1])); \
    float oo2 = __builtin_fmaf(bflo((U)[2]), h, bfhi((U)[2])); \
    float gb  = __builtin_fmaf(bflo((U)[3]), h, bfhi((U)[3])); \
    float ign = ia * gb; \
    float negoo = -0.5f * oo2; \
    c2 = __builtin_fmaf(fh, c2, ign); \
    float rt = __builtin_amdgcn_rcpf(1.f + __builtin_amdgcn_exp2f(c2)); \
    h = __builtin_fmaf(oo2, rt, negoo); \
    cval = c2 * CK; \
} while (0)

__global__ __launch_bounds__(128) void lstm_scan(const u32* __restrict__ coef,
                                                 float* __restrict__ h_out,
                                                 float* __restrict__ c_out) {
    __shared__ u32 lds[2][CHUNK][256];   // 64 KiB -> 2 blocks/CU
    const int tid = threadIdx.x;
    const int lane = tid & 63;
    const int blk_ch = blockIdx.x & 7;
    const int chunk = blockIdx.x >> 3;
    const int warm = (chunk == 0) ? 0 : WARMCH;
    const long tstart = (long)chunk * LCHUNK - (long)warm * CHUNK;
    const int NC = LCHUNK / CHUNK + warm;       // 8 or 10

    if (tid >= 64) {
        const u32* src = coef + tstart * NGEMM + (lane >> 4) * SDIM + blk_ch * 64 + (lane & 15) * 4;
        #pragma unroll 8
        for (int j = 0; j < CHUNK; ++j)
            gload_lds16(src + (long)j * NGEMM, &lds[0][j][0]);
        __syncthreads();
        for (int k = 0; k < NC; ++k) {
            if (k + 1 < NC) {
                const u32* s2 = src + (long)(k + 1) * CHUNK * NGEMM;
                u32* dst = &lds[(k + 1) & 1][0][0];
                #pragma unroll 8
                for (int j = 0; j < CHUNK; ++j)
                    gload_lds16(s2 + (long)j * NGEMM, dst + j * 256);
            }
            __syncthreads();
        }
        return;
    }

    // consumer: permuted channel ownership
    const int s = blk_ch * 64 + (lane & 3) * 16 + (lane >> 2);
    const float CK = -0.34657359027997264f;  // -ln2/2: c = CK * c2
    if (chunk == 0) { h_out[s] = 0.f; c_out[s] = 0.f; }
    float h = 0.f, c2 = 0.f, cval = 0.f;
    float* hp = h_out + SDIM + s;
    float* cp = c_out + SDIM + s;

    __syncthreads();   // chunk 0 ready
    for (int k = 0; k < NC; ++k) {
        const u32* Ld = &lds[k & 1][0][0];
        u32 R[PF][4];
        #pragma unroll
        for (int p = 0; p < PF; ++p) {
            R[p][0] = Ld[p * 256 + lane];
            R[p][1] = Ld[p * 256 + 64 + lane];
            R[p][2] = Ld[p * 256 + 128 + lane];
            R[p][3] = Ld[p * 256 + 192 + lane];
        }
        const long tbase = tstart + (long)k * CHUNK;
        if (k < warm) {
            #pragma unroll
            for (int j = 0; j < CHUNK; ++j) {
                STEP(R[j & (PF - 1)]);
                if (j < CHUNK - PF) {
                    R[j & (PF - 1)][0] = Ld[(j + PF) * 256 + lane];
                    R[j & (PF - 1)][1] = Ld[(j + PF) * 256 + 64 + lane];
                    R[j & (PF - 1)][2] = Ld[(j + PF) * 256 + 128 + lane];
                    R[j & (PF - 1)][3] = Ld[(j + PF) * 256 + 192 + lane];
                }
            }
        } else {
            #pragma unroll
            for (int j = 0; j < CHUNK; ++j) {
                STEP(R[j & (PF - 1)]);
                hp[(tbase + j) * SDIM] = h;
                cp[(tbase + j) * SDIM] = cval;
                if (j < CHUNK - PF) {
                    R[j & (PF - 1)][0] = Ld[(j + PF) * 256 + lane];
                    R[j & (PF - 1)][1] = Ld[(j + PF) * 256 + 64 + lane];
                    R[j & (PF - 1)][2] = Ld[(j + PF) * 256 + 128 + lane];
                    R[j & (PF - 1)][3] = Ld[(j + PF) * 256 + 192 + lane];
                }
            }
        }
        __syncthreads();
    }
}

// ---------- q_t = h_n[1:] @ W_reg^T + b_reg : one wave per timestep ----------
__global__ __launch_bounds__(256) void q_kernel(const float* __restrict__ h_n,
                                                const float* __restrict__ wreg,
                                                const float* __restrict__ breg,
                                                float* __restrict__ q) {
    int gw = (blockIdx.x * blockDim.x + threadIdx.x) >> 6;  // t
    int lane = threadIdx.x & 63;
    if (gw >= T_STEPS) return;
    const float* row = h_n + (long)(gw + 1) * SDIM;
    float sum = 0.f;
    #pragma unroll
    for (int j = 0; j < 8; ++j)
        sum += row[lane + j * 64] * wreg[lane + j * 64];
    #pragma unroll
    for (int off = 32; off > 0; off >>= 1)
        sum += __shfl_down(sum, off, 64);
    if (lane == 0) q[gw] = sum + breg[0];
}

extern "C" void kernel_launch(void* const* d_in, const int* in_sizes, int n_in,
                              void* d_out, int out_size, void* d_ws, size_t ws_size,
                              hipStream_t stream) {
    const float* x     = (const float*)d_in[0];   // (16384,1024)
    const float* w_in  = (const float*)d_in[1];   // (512,4,1024)
    const float* w_rec = (const float*)d_in[2];   // (4,512)
    const float* bias  = (const float*)d_in[3];   // (4,512)
    const float* w_reg = (const float*)d_in[4];   // (1,512)
    const float* b_reg = (const float*)d_in[5];   // (1,)

    float* out = (float*)d_out;
    float* q   = out;                               // 16384
    float* h_n = out + T_STEPS;                     // 16385*512
    float* c_n = h_n + (long)(T_STEPS + 1) * SDIM;  // 16385*512

    char* ws = (char*)d_ws;
    const size_t COEF_BYTES = (size_t)T_STEPS * NGEMM * 4;   // 134217728
    const size_t XB_BYTES   = (size_t)T_STEPS * INP * 2;     // 33554432
    u32* coef = (u32*)ws;
    u16* xb   = (u16*)(ws + COEF_BYTES);
    u16* wb   = (u16*)(ws + COEF_BYTES + XB_BYTES);

    cvt_x<<<4096, 256, 0, stream>>>(x, xb, (long)T_STEPS * INP / 4);
    pack_w<<<2048, 256, 0, stream>>>(w_in, wb);
    gemm_bt<<<(T_STEPS / 256) * (NGEMM / 256), 512, 0, stream>>>(xb, wb, w_rec, bias, coef, T_STEPS, NGEMM, INP);
    lstm_scan<<<8 * NPAR, 128, 0, stream>>>(coef, h_n, c_n);
    q_kernel<<<(T_STEPS * 64) / 256, 256, 0, stream>>>(h_n, w_reg, b_reg, q);
}

// Round 18
// 142.037 us; speedup vs baseline: 1.1120x; 1.0205x over previous
//
#include <hip/hip_runtime.h>

typedef unsigned short u16;
typedef unsigned int u32;
typedef __attribute__((ext_vector_type(4))) unsigned short u16x4;
typedef __attribute__((ext_vector_type(8))) short short8;
typedef __attribute__((ext_vector_type(8))) __bf16 bf16x8;
typedef __attribute__((ext_vector_type(4))) float f32x4;

#define T_STEPS 16384
#define INP 1024
#define SDIM 512
#define NGEMM 2048   // 4 gates * 512
#define L2E 1.4426950408889634f

__device__ __forceinline__ u16 f2bf(float f) {
    unsigned u = __float_as_uint(f);
    return (u16)((u + 0x7fffu + ((u >> 16) & 1u)) >> 16);
}
__device__ __forceinline__ float bfhi(u32 d) { return __uint_as_float(d & 0xffff0000u); }
__device__ __forceinline__ float bflo(u32 d) { return __uint_as_float(d << 16); }

__device__ __forceinline__ void gload_lds16(const void* g, void* l) {
    __builtin_amdgcn_global_load_lds((const __attribute__((address_space(1))) unsigned*)g,
                                     (__attribute__((address_space(3))) unsigned*)l, 16, 0, 0);
}

// ---------- convert x (T,1024) fp32 -> bf16 ----------
__global__ void cvt_x(const float* __restrict__ x, u16* __restrict__ xb, long n4) {
    long i = (long)blockIdx.x * blockDim.x + threadIdx.x;
    long stride = (long)gridDim.x * blockDim.x;
    for (; i < n4; i += stride) {
        float4 v = ((const float4*)x)[i];
        u16x4 o;
        o.x = f2bf(v.x); o.y = f2bf(v.y); o.z = f2bf(v.z); o.w = f2bf(v.w);
        ((u16x4*)xb)[i] = o;
    }
}

// ---------- pack weight_input (512,4,1024) fp32 -> bf16 (2048,1024) with n = g*512+s ----------
__global__ void pack_w(const float* __restrict__ w, u16* __restrict__ wb) {
    int id = blockIdx.x * blockDim.x + threadIdx.x;
    int kv = id & 255;          // k/4
    int n  = id >> 8;           // 0..2047
    int g = n >> 9, s = n & 511;
    const float4 v = *(const float4*)(w + ((long)(s * 4 + g)) * INP + kv * 4);
    u16x4 o;
    o.x = f2bf(v.x); o.y = f2bf(v.y); o.z = f2bf(v.z); o.w = f2bf(v.w);
    *(u16x4*)(wb + (long)n * INP + kv * 4) = o;
}

// ---------- GEMM: 256x256, 8 waves, 5-BUF ring, READ-AHEAD INTERLEAVED IN MFMA BURST ----------
// ITER(t): for m=0..7 { 4 MFMA (row m, tile t, frags read at iter t-1) ;
//                       ds_read afr[m] <- buf (t+1)%5 }          // afr[m] dead after its row
//          ds_read bfr[0..3] <- buf (t+1)%5                       // bfr dead after row 7
//          vmcnt(4) ; STAGE(tile t+3 -> buf (t+3)%5) ; barrier
// DS reads now issue DURING the MFMA drain (WAR on afr[m] resolved by program
// order; SSA ranges don't overlap -> regalloc reuses the same 48 frag VGPRs,
// +0 register pressure at our 252/256 budget). The post-barrier read storm is
// gone: iter t+1's operands were loaded one iter early; its first MFMA waits
// only the tail bfr reads (covered by vmcnt+barrier latency).
// Visibility: reads of buf (t+1)%5 at ITER(t) are legal because vmcnt@t-1
// retired tile t+1 locally and barrier(t-1) published it. Prologue therefore
// waits vmcnt(4) (retires tiles 0 AND 1) before the initial READ12(buf0).
// vmcnt ladder (4 loads/iter, FIFO): ITER(t) outstanding before wait =
// {t+2 (staged t-1), t+3 (this iter)} = 8 -> vmcnt(4) retires tile t+2, which
// ITER(t+1) reads. Tail: t=28 {30,31}->vm4 retires 30; t=29 vm0 retires 31;
// t=30 nothing outstanding. Stage safety: target buf (t+3)%5 == (t-2)%5 was
// last READ at iter t-3; those reads retired before MFMA(t-2) issue (compiler
// lgkm precedes use), and every wave past barrier(t-1) has issued MFMA(t-1) >
// MFMA(t-2) => 2-barrier margin before the DMA lands.
// Swizzle (R7, conflicts=0). XCD swizzle: 512 blocks %8==0. Epilogue: permuted
// coef layout, uint4 stores (WRITE_SIZE verified exactly 131072 KB).
__global__ __launch_bounds__(512, 2) void gemm_bt(const u16* __restrict__ A,
                                                  const u16* __restrict__ B,
                                                  const float* __restrict__ wrec,
                                                  const float* __restrict__ bsv,
                                                  u32* __restrict__ coef,
                                                  int M, int N, int K) {
    __shared__ u16 sA[5][256 * 32];
    __shared__ u16 sB[5][256 * 32];
    const int tid = threadIdx.x;
    const int nbx = N >> 8;                 // 8
    const int nwg = gridDim.x;              // 512
    const int cpx = nwg >> 3;
    const int bid = ((int)blockIdx.x & 7) * cpx + ((int)blockIdx.x >> 3);
    const int bx = bid % nbx, by = bid / nbx;
    const long brow = (long)by << 8, bcol = (long)bx << 8;
    const int w = tid >> 6, lane = tid & 63;
    const int wr = w >> 2, wc = w & 3;      // 2 x 4 waves
    const int r16 = lane & 15, kq = lane >> 4;

    // staging: each wave stages rows [w*32, w*32+32) of A and B (2 gloads each)
    const int row0  = w * 32 + (lane >> 2);
    const int sslot = lane & 3;
    const int chs   = sslot ^ ((row0 >> 1) & 3);
    const u16* gA0 = A + (brow + row0) * (long)K + chs * 8;
    const u16* gA1 = gA0 + 16 * (long)K;
    const u16* gB0 = B + (bcol + row0) * (long)K + chs * 8;
    const u16* gB1 = gB0 + 16 * (long)K;
    const int dst0 = row0 * 32 + sslot * 8;
    const int dst1 = dst0 + 16 * 32;

    const int slotR = kq ^ ((r16 >> 1) & 3);
    int aoff[8], boff[4];
    #pragma unroll
    for (int m = 0; m < 8; ++m)
        aoff[m] = (wr * 128 + m * 16 + r16) * 32 + slotR * 8;
    #pragma unroll
    for (int n = 0; n < 4; ++n)
        boff[n] = (wc * 64 + n * 16 + r16) * 32 + slotR * 8;

    f32x4 acc[8][4] = {};
    bf16x8 afr[8], bfr[4];   // single-buffered frags; read-ahead reuses them

#define STAGE(BUF, koff) do { \
        gload_lds16(gA0 + (koff), &sA[BUF][dst0]); \
        gload_lds16(gA1 + (koff), &sA[BUF][dst1]); \
        gload_lds16(gB0 + (koff), &sB[BUF][dst0]); \
        gload_lds16(gB1 + (koff), &sB[BUF][dst1]); \
    } while (0)

#define ITER(BNXT, SBUF, SKOFF, WAITSTR, DOSTAGE, DOREAD) do { \
        __builtin_amdgcn_s_setprio(1); \
        _Pragma("unroll") for (int m_ = 0; m_ < 8; ++m_) { \
            _Pragma("unroll") for (int n_ = 0; n_ < 4; ++n_) \
                acc[m_][n_] = __builtin_amdgcn_mfma_f32_16x16x32_bf16(afr[m_], bfr[n_], acc[m_][n_], 0, 0, 0); \
            if (DOREAD) afr[m_] = *(const bf16x8*)&sA[BNXT][aoff[m_]]; \
        } \
        __builtin_amdgcn_s_setprio(0); \
        if (DOREAD) { \
            _Pragma("unroll") for (int n_ = 0; n_ < 4; ++n_) \
                bfr[n_] = *(const bf16x8*)&sB[BNXT][boff[n_]]; \
        } \
        asm volatile(WAITSTR ::: "memory"); \
        if (DOSTAGE) { STAGE(SBUF, SKOFF); } \
        __builtin_amdgcn_s_barrier(); \
    } while (0)

    // prologue: tiles 0,1,2 -> bufs 0,1,2 (12 loads); vmcnt(4) retires tiles 0 AND 1
    STAGE(0, 0);
    STAGE(1, 32);
    STAGE(2, 64);
    asm volatile("s_waitcnt vmcnt(4)" ::: "memory");
    __builtin_amdgcn_s_barrier();
    // initial frag load: tile 0
    afr[0] = *(const bf16x8*)&sA[0][aoff[0]];
    #pragma unroll
    for (int n_ = 0; n_ < 4; ++n_) bfr[n_] = *(const bf16x8*)&sB[0][boff[n_]];
    #pragma unroll
    for (int m_ = 1; m_ < 8; ++m_) afr[m_] = *(const bf16x8*)&sA[0][aoff[m_]];

    // main: t=0..24 (x5 unroll); ITER(t) computes tile t, reads tile t+1, stages t+3
    #pragma unroll 1
    for (int t = 0; t < 25; t += 5) {
        ITER(1, 3, (t + 3) * 32, "s_waitcnt vmcnt(4)", 1, 1);
        ITER(2, 4, (t + 4) * 32, "s_waitcnt vmcnt(4)", 1, 1);
        ITER(3, 0, (t + 5) * 32, "s_waitcnt vmcnt(4)", 1, 1);
        ITER(4, 1, (t + 6) * 32, "s_waitcnt vmcnt(4)", 1, 1);
        ITER(0, 2, (t + 7) * 32, "s_waitcnt vmcnt(4)", 1, 1);
    }
    ITER(1, 3, 28 * 32, "s_waitcnt vmcnt(4)", 1, 1);   // t=25: stage 28
    ITER(2, 4, 29 * 32, "s_waitcnt vmcnt(4)", 1, 1);   // t=26: stage 29
    ITER(3, 0, 30 * 32, "s_waitcnt vmcnt(4)", 1, 1);   // t=27: stage 30
    ITER(4, 1, 31 * 32, "s_waitcnt vmcnt(4)", 1, 1);   // t=28: stage 31
    ITER(0, 0, 0,       "s_waitcnt vmcnt(0)", 0, 1);   // t=29: retire 31; read tile 30 (buf0)
    ITER(1, 0, 0,       "s_waitcnt vmcnt(0)", 0, 1);   // t=30: read tile 31 (buf1)
    {   // t=31: MFMA only (frags hold tile 31)
        __builtin_amdgcn_s_setprio(1);
        #pragma unroll
        for (int m_ = 0; m_ < 8; ++m_)
            #pragma unroll
            for (int n_ = 0; n_ < 4; ++n_)
                acc[m_][n_] = __builtin_amdgcn_mfma_f32_16x16x32_bf16(afr[m_], bfr[n_], acc[m_][n_], 0, 0, 0);
        __builtin_amdgcn_s_setprio(0);
    }
#undef ITER
#undef STAGE

    // ---- epilogue: linearized coeffs, PERMUTED layout, coalesced uint4 stores ----
    const int g = (int)(bcol >> 9);                  // block-uniform gate
    float wvv[4], bvv[4];
    #pragma unroll
    for (int n = 0; n < 4; ++n) {
        long col = bcol + wc * 64 + n * 16 + r16;
        wvv[n] = wrec[col]; bvv[n] = bsv[col];
    }
    #pragma unroll
    for (int m = 0; m < 8; ++m) {
        #pragma unroll
        for (int j = 0; j < 4; ++j) {
            u32 pk[4];
            #pragma unroll
            for (int n = 0; n < 4; ++n) {
                float z0 = acc[m][n][j] + bvv[n];
                if (g == 3) {
                    float et = __builtin_amdgcn_exp2f(-2.f * L2E * z0);
                    float r = __builtin_amdgcn_rcpf(1.f + et);
                    float t = __builtin_fmaf(2.f, r, -1.f);
                    pk[n] = ((u32)f2bf(t) << 16) | f2bf((1.f - t * t) * wvv[n]);
                } else {
                    float e = __builtin_amdgcn_exp2f(-L2E * z0);
                    float r = __builtin_amdgcn_rcpf(1.f + e);
                    float kk = (g == 0) ? 1.f : ((g == 1) ? (-2.f * L2E) : 2.f);
                    float C0 = kk * r;
                    pk[n] = ((u32)f2bf(C0) << 16) | f2bf(C0 * r * e * wvv[n]);
                }
            }
            long row = brow + wr * 128 + m * 16 + kq * 4 + j;
            uint4 v4; v4.x = pk[0]; v4.y = pk[1]; v4.z = pk[2]; v4.w = pk[3];
            *(uint4*)(coef + row * NGEMM + bcol + wc * 64 + r16 * 4) = v4;
        }
    }
}

// ---------- diagonal LSTM scan, parallel-in-time (R16: 64 chunks x 8 groups) ----------
// LCHUNK=256 with 64-step warm-up (2 chunks of 32); LDS ring 2x32x1KB = 64KiB
// -> 2 blocks/CU, all 512 blocks co-resident; serial length 320 steps.
// Consumer lane L owns channel s_own = blk64 + (L&3)*16 + (L>>2) (permuted coef).
#define CHUNK 32
#define LCHUNK 256
#define NPAR (T_STEPS / LCHUNK)   // 64
#define WARMCH 2                  // warm-up chunks (64 steps)
#define PF 4

#define STEP(U) do { \
    float fh  = __builtin_fmaf(bflo((U)[0]), h, bfhi((U)[0])); \
    float ia  = __builtin_fmaf(bflo((U)[1]), h, bfhi((U)[1])); \
    float oo2 = __builtin_fmaf(bflo((U)[2]), h, bfhi((U)[2])); \
    float gb  = __builtin_fmaf(bflo((U)[3]), h, bfhi((U)[3])); \
    float ign = ia * gb; \
    float negoo = -0.5f * oo2; \
    c2 = __builtin_fmaf(fh, c2, ign); \
    float rt = __builtin_amdgcn_rcpf(1.f + __builtin_amdgcn_exp2f(c2)); \
    h = __builtin_fmaf(oo2, rt, negoo); \
    cval = c2 * CK; \
} while (0)

__global__ __launch_bounds__(128) void lstm_scan(const u32* __restrict__ coef,
                                                 float* __restrict__ h_out,
                                                 float* __restrict__ c_out) {
    __shared__ u32 lds[2][CHUNK][256];   // 64 KiB -> 2 blocks/CU
    const int tid = threadIdx.x;
    const int lane = tid & 63;
    const int blk_ch = blockIdx.x & 7;
    const int chunk = blockIdx.x >> 3;
    const int warm = (chunk == 0) ? 0 : WARMCH;
    const long tstart = (long)chunk * LCHUNK - (long)warm * CHUNK;
    const int NC = LCHUNK / CHUNK + warm;       // 8 or 10

    if (tid >= 64) {
        const u32* src = coef + tstart * NGEMM + (lane >> 4) * SDIM + blk_ch * 64 + (lane & 15) * 4;
        #pragma unroll 8
        for (int j = 0; j < CHUNK; ++j)
            gload_lds16(src + (long)j * NGEMM, &lds[0][j][0]);
        __syncthreads();
        for (int k = 0; k < NC; ++k) {
            if (k + 1 < NC) {
                const u32* s2 = src + (long)(k + 1) * CHUNK * NGEMM;
                u32* dst = &lds[(k + 1) & 1][0][0];
                #pragma unroll 8
                for (int j = 0; j < CHUNK; ++j)
                    gload_lds16(s2 + (long)j * NGEMM, dst + j * 256);
            }
            __syncthreads();
        }
        return;
    }

    // consumer: permuted channel ownership
    const int s = blk_ch * 64 + (lane & 3) * 16 + (lane >> 2);
    const float CK = -0.34657359027997264f;  // -ln2/2: c = CK * c2
    if (chunk == 0) { h_out[s] = 0.f; c_out[s] = 0.f; }
    float h = 0.f, c2 = 0.f, cval = 0.f;
    float* hp = h_out + SDIM + s;
    float* cp = c_out + SDIM + s;

    __syncthreads();   // chunk 0 ready
    for (int k = 0; k < NC; ++k) {
        const u32* Ld = &lds[k & 1][0][0];
        u32 R[PF][4];
        #pragma unroll
        for (int p = 0; p < PF; ++p) {
            R[p][0] = Ld[p * 256 + lane];
            R[p][1] = Ld[p * 256 + 64 + lane];
            R[p][2] = Ld[p * 256 + 128 + lane];
            R[p][3] = Ld[p * 256 + 192 + lane];
        }
        const long tbase = tstart + (long)k * CHUNK;
        if (k < warm) {
            #pragma unroll
            for (int j = 0; j < CHUNK; ++j) {
                STEP(R[j & (PF - 1)]);
                if (j < CHUNK - PF) {
                    R[j & (PF - 1)][0] = Ld[(j + PF) * 256 + lane];
                    R[j & (PF - 1)][1] = Ld[(j + PF) * 256 + 64 + lane];
                    R[j & (PF - 1)][2] = Ld[(j + PF) * 256 + 128 + lane];
                    R[j & (PF - 1)][3] = Ld[(j + PF) * 256 + 192 + lane];
                }
            }
        } else {
            #pragma unroll
            for (int j = 0; j < CHUNK; ++j) {
                STEP(R[j & (PF - 1)]);
                hp[(tbase + j) * SDIM] = h;
                cp[(tbase + j) * SDIM] = cval;
                if (j < CHUNK - PF) {
                    R[j & (PF - 1)][0] = Ld[(j + PF) * 256 + lane];
                    R[j & (PF - 1)][1] = Ld[(j + PF) * 256 + 64 + lane];
                    R[j & (PF - 1)][2] = Ld[(j + PF) * 256 + 128 + lane];
                    R[j & (PF - 1)][3] = Ld[(j + PF) * 256 + 192 + lane];
                }
            }
        }
        __syncthreads();
    }
}

// ---------- q_t = h_n[1:] @ W_reg^T + b_reg : one wave per timestep ----------
__global__ __launch_bounds__(256) void q_kernel(const float* __restrict__ h_n,
                                                const float* __restrict__ wreg,
                                                const float* __restrict__ breg,
                                                float* __restrict__ q) {
    int gw = (blockIdx.x * blockDim.x + threadIdx.x) >> 6;  // t
    int lane = threadIdx.x & 63;
    if (gw >= T_STEPS) return;
    const float* row = h_n + (long)(gw + 1) * SDIM;
    float sum = 0.f;
    #pragma unroll
    for (int j = 0; j < 8; ++j)
        sum += row[lane + j * 64] * wreg[lane + j * 64];
    #pragma unroll
    for (int off = 32; off > 0; off >>= 1)
        sum += __shfl_down(sum, off, 64);
    if (lane == 0) q[gw] = sum + breg[0];
}

extern "C" void kernel_launch(void* const* d_in, const int* in_sizes, int n_in,
                              void* d_out, int out_size, void* d_ws, size_t ws_size,
                              hipStream_t stream) {
    const float* x     = (const float*)d_in[0];   // (16384,1024)
    const float* w_in  = (const float*)d_in[1];   // (512,4,1024)
    const float* w_rec = (const float*)d_in[2];   // (4,512)
    const float* bias  = (const float*)d_in[3];   // (4,512)
    const float* w_reg = (const float*)d_in[4];   // (1,512)
    const float* b_reg = (const float*)d_in[5];   // (1,)

    float* out = (float*)d_out;
    float* q   = out;                               // 16384
    float* h_n = out + T_STEPS;                     // 16385*512
    float* c_n = h_n + (long)(T_STEPS + 1) * SDIM;  // 16385*512

    char* ws = (char*)d_ws;
    const size_t COEF_BYTES = (size_t)T_STEPS * NGEMM * 4;   // 134217728
    const size_t XB_BYTES   = (size_t)T_STEPS * INP * 2;     // 33554432
    u32* coef = (u32*)ws;
    u16* xb   = (u16*)(ws + COEF_BYTES);
    u16* wb   = (u16*)(ws + COEF_BYTES + XB_BYTES);

    cvt_x<<<4096, 256, 0, stream>>>(x, xb, (long)T_STEPS * INP / 4);
    pack_w<<<2048, 256, 0, stream>>>(w_in, wb);
    gemm_bt<<<(T_STEPS / 256) * (NGEMM / 256), 512, 0, stream>>>(xb, wb, w_rec, bias, coef, T_STEPS, NGEMM, INP);
    lstm_scan<<<8 * NPAR, 128, 0, stream>>>(coef, h_n, c_n);
    q_kernel<<<(T_STEPS * 64) / 256, 256, 0, stream>>>(h_n, w_reg, b_reg, q);
}